// Round 5
// baseline (816.564 us; speedup 1.0000x reference)
//
#include <hip/hip_runtime.h>
#include <hip/hip_bf16.h>

typedef __attribute__((ext_vector_type(8))) short short8;
typedef __attribute__((ext_vector_type(4))) float f32x4;

#define DEVI static __device__ __forceinline__

constexpr int HID = 1024;
constexpr int BB = 4, LL = 4096;
constexpr int MROWS = BB * LL;   // 16384
constexpr int FF = 4 * HID;      // 4096
constexpr int NCH = 64, TCH = 64;  // scan chunking

// ---------------- ws layout (bytes) ----------------
constexpr size_t ELN_EMB = 0;                 // 16M elems
constexpr size_t ELN_WA  = 16777216;
constexpr size_t ELN_WB  = ELN_WA + 1048576;
constexpr size_t ELN_WO  = ELN_WB + 1048576;
constexpr size_t ELN_CW  = ELN_WO + 1048576;
constexpr size_t ELN_F1  = ELN_CW + 1048576;
constexpr size_t ELN_F2  = ELN_F1 + 4194304;
constexpr size_t ELN_PW  = ELN_F2 + 4194304;
constexpr size_t ELN_END = ELN_PW + 1048576;  // 30,408,704 elems
constexpr size_t POOL_BYTES = ELN_END * 2;    // 60,817,408 B

constexpr size_t REG = 33554432;              // 32MB per activation region
constexpr size_t OFF_U  = POOL_BYTES;          // u bf16
constexpr size_t OFF_AZ = OFF_U  + REG;        // a, later z, later ffn(lo)
constexpr size_t OFF_W2 = OFF_AZ + REG;        // w, later ffn(hi)
constexpr size_t OFF_H2 = OFF_W2 + REG;        // h, later v
constexpr size_t OFF_B2 = OFF_H2 + REG;        // b
constexpr size_t OFF_AGG = OFF_B2 + REG;       // scan aggregates
constexpr size_t AG_ELEMS = (size_t)BB * NCH * HID;  // 262144
constexpr size_t WS_NEEDED = OFF_AGG + AG_ELEMS * 4 * 3;  // ~231.7MB

// ---------------- helpers ----------------
DEVI unsigned short f2b(float x) {            // f32 -> bf16 RNE
  unsigned u = __float_as_uint(x);
  return (unsigned short)((u + 0x7fffu + ((u >> 16) & 1u)) >> 16);
}
DEVI float b2f(unsigned short u) { return __uint_as_float((unsigned)u << 16); }

DEVI void gload_lds16(const unsigned short* g, unsigned short* l) {
  // direct addrspacecasts: compiler lowers generic->as(3) correctly (strips aperture)
  __builtin_amdgcn_global_load_lds(
      (const __attribute__((address_space(1))) void*)g,
      (__attribute__((address_space(3))) void*)l, 16, 0, 0);
}

// ---------------- f32 -> bf16 conversion of emb + all weights ----------------
constexpr long CH_EMB = 16777216 / 8;
constexpr long CH_W   = 1048576 / 8;
constexpr long CH_F   = 4194304 / 8;
constexpr long SEG1 = CH_EMB;
constexpr long SEG2 = SEG1 + CH_W;
constexpr long SEG3 = SEG2 + CH_W;
constexpr long SEG4 = SEG3 + CH_W;
constexpr long SEG5 = SEG4 + CH_W;
constexpr long SEG6 = SEG5 + CH_F;
constexpr long SEG7 = SEG6 + CH_F;
constexpr long SEG8 = SEG7 + CH_W;

__global__ __launch_bounds__(256) void convert_all(
    const float* __restrict__ emb, const float* __restrict__ wa,
    const float* __restrict__ wb,  const float* __restrict__ wo,
    const float* __restrict__ cw,  const float* __restrict__ f1,
    const float* __restrict__ f2,  const float* __restrict__ pw,
    unsigned short* __restrict__ dst) {
  const long stride = (long)gridDim.x * blockDim.x;
  for (long ck = (long)blockIdx.x * blockDim.x + threadIdx.x; ck < SEG8; ck += stride) {
    const float* s; size_t d;
    if (ck < SEG1)      { s = emb + (size_t)ck * 8;        d = ELN_EMB + (size_t)ck * 8; }
    else if (ck < SEG2) { s = wa + (size_t)(ck-SEG1) * 8;  d = ELN_WA + (size_t)(ck-SEG1) * 8; }
    else if (ck < SEG3) { s = wb + (size_t)(ck-SEG2) * 8;  d = ELN_WB + (size_t)(ck-SEG2) * 8; }
    else if (ck < SEG4) { s = wo + (size_t)(ck-SEG3) * 8;  d = ELN_WO + (size_t)(ck-SEG3) * 8; }
    else if (ck < SEG5) { s = cw + (size_t)(ck-SEG4) * 8;  d = ELN_CW + (size_t)(ck-SEG4) * 8; }
    else if (ck < SEG6) { s = f1 + (size_t)(ck-SEG5) * 8;  d = ELN_F1 + (size_t)(ck-SEG5) * 8; }
    else if (ck < SEG7) { s = f2 + (size_t)(ck-SEG6) * 8;  d = ELN_F2 + (size_t)(ck-SEG6) * 8; }
    else                { s = pw + (size_t)(ck-SEG7) * 8;  d = ELN_PW + (size_t)(ck-SEG7) * 8; }
    float4 x = *(const float4*)s;
    float4 y = *(const float4*)(s + 4);
    short8 o;
    o[0]=(short)f2b(x.x); o[1]=(short)f2b(x.y); o[2]=(short)f2b(x.z); o[3]=(short)f2b(x.w);
    o[4]=(short)f2b(y.x); o[5]=(short)f2b(y.y); o[6]=(short)f2b(y.z); o[7]=(short)f2b(y.w);
    *(short8*)(dst + d) = o;
  }
}

// ---------------- GEMM: C = A(MxK) * W(NxK)^T, 128x128 tile, global_load_lds ----
// EPI: 0 tanh->bf16 | 1 +bias->bf16 | 2 z=hw*(acc+bias+add)->bf16
//      3 gelu->bf16 | 4 acc+bias+add->bf16 | 5 +bias->f32
template <int EPI>
__global__ __launch_bounds__(256) void gemm_bt(
    const unsigned short* __restrict__ A, const unsigned short* __restrict__ Bw,
    int K, int N,
    const float* __restrict__ bias, const unsigned short* __restrict__ addB,
    const float* __restrict__ hw,
    float* __restrict__ outF, unsigned short* __restrict__ outB) {
  __shared__ alignas(16) unsigned short ldsA[128 * 32];
  __shared__ alignas(16) unsigned short ldsB[128 * 32];
  const int tid = threadIdx.x;
  const int lane = tid & 63, wave = tid >> 6;
  const int wr = wave >> 1, wc = wave & 1;           // wave -> 64x64 subtile
  const int arow0 = blockIdx.x * 128, bcol0 = blockIdx.y * 128;
  f32x4 acc[4][4] = {};
  const int fm = lane & 15, fk = (lane >> 4) * 8;    // fragment coords
  const int skb = (tid & 3) * 8;                     // staging coords (row = tid>>2)
  const unsigned short* Ag = A + (size_t)(arow0 + (tid >> 2)) * K + skb;
  const unsigned short* Bg = Bw + (size_t)(bcol0 + (tid >> 2)) * K + skb;
  const size_t rowskip = (size_t)64 * K;
  for (int k0 = 0; k0 < K; k0 += 32) {
    // m97 structure: async global->LDS, barrier (drains vmcnt), ds_read+MFMA, barrier
    gload_lds16(Ag + k0,           &ldsA[tid * 8]);
    gload_lds16(Ag + k0 + rowskip, &ldsA[2048 + tid * 8]);
    gload_lds16(Bg + k0,           &ldsB[tid * 8]);
    gload_lds16(Bg + k0 + rowskip, &ldsB[2048 + tid * 8]);
    __syncthreads();
    short8 af[4], bfr[4];
#pragma unroll
    for (int i = 0; i < 4; ++i) {
      af[i]  = *(const short8*)&ldsA[(wr * 64 + i * 16 + fm) * 32 + fk];
      bfr[i] = *(const short8*)&ldsB[(wc * 64 + i * 16 + fm) * 32 + fk];
    }
#pragma unroll
    for (int i = 0; i < 4; ++i)
#pragma unroll
      for (int j = 0; j < 4; ++j)
        acc[i][j] = __builtin_amdgcn_mfma_f32_16x16x32_bf16(af[i], bfr[j], acc[i][j], 0, 0, 0);
    __syncthreads();
  }
  // epilogue: D row = (lane>>4)*4 + reg, col = lane&15  [m89-verified]
  const int m0 = arow0 + wr * 64, n0 = bcol0 + wc * 64;
  const int crow = (lane >> 4) * 4, ccol = lane & 15;
#pragma unroll
  for (int i = 0; i < 4; ++i) {
#pragma unroll
    for (int j = 0; j < 4; ++j) {
      const int col = n0 + j * 16 + ccol;
      const float bv = bias[col];
      float hwv = 1.f;
      if constexpr (EPI == 2) hwv = hw[col >> 6];
#pragma unroll
      for (int r = 0; r < 4; ++r) {
        const int row = m0 + i * 16 + crow + r;
        const size_t idx = (size_t)row * N + col;
        float x = acc[i][j][r] + bv;
        if constexpr (EPI == 0) outB[idx] = f2b(tanhf(x));
        else if constexpr (EPI == 1) outB[idx] = f2b(x);
        else if constexpr (EPI == 2) outB[idx] = f2b(hwv * (x + b2f(addB[idx])));
        else if constexpr (EPI == 3) {
          float gl = 0.5f * x * (1.f + erff(x * 0.70710678118654752f));
          outB[idx] = f2b(gl);
        } else if constexpr (EPI == 4) outB[idx] = f2b(x + b2f(addB[idx]));
        else outF[idx] = x;
      }
    }
  }
}

// ---------------- chunked affine scan: h_t = a_t*h_{t-1} + b_t ----------------
__global__ __launch_bounds__(256) void scan_p1(const unsigned short* __restrict__ a,
                                               const unsigned short* __restrict__ bsrc,
                                               float* __restrict__ agA,
                                               float* __restrict__ agB) {
  const int idx = blockIdx.x;
  const int cg = idx & 3, ch = (idx >> 2) & (NCH - 1), bb = idx >> 8;
  const int c = cg * 256 + threadIdx.x;
  const size_t base = ((size_t)bb * LL + (size_t)ch * TCH) * HID + c;
  float A = 1.f, Bg = 0.f;
#pragma unroll 4
  for (int t = 0; t < TCH; ++t) {
    float at = b2f(a[base + (size_t)t * HID]);
    float bt = b2f(bsrc[base + (size_t)t * HID]);
    Bg = fmaf(at, Bg, bt);
    A *= at;
  }
  const size_t o = ((size_t)bb * NCH + ch) * HID + c;
  agA[o] = A;
  agB[o] = Bg;
}

__global__ __launch_bounds__(256) void scan_p2(const float* __restrict__ agA,
                                               const float* __restrict__ agB,
                                               float* __restrict__ pre) {
  const int gid = blockIdx.x * 256 + threadIdx.x;  // 4096 = BB*HID
  const int bb = gid >> 10, c = gid & 1023;
  float h = 0.f;
  for (int ch = 0; ch < NCH; ++ch) {
    const size_t o = ((size_t)bb * NCH + ch) * HID + c;
    pre[o] = h;
    h = fmaf(agA[o], h, agB[o]);
  }
}

__global__ __launch_bounds__(256) void scan_p3(const unsigned short* __restrict__ a,
                                               const unsigned short* __restrict__ bsrc,
                                               const float* __restrict__ pre,
                                               unsigned short* __restrict__ hout) {
  const int idx = blockIdx.x;
  const int cg = idx & 3, ch = (idx >> 2) & (NCH - 1), bb = idx >> 8;
  const int c = cg * 256 + threadIdx.x;
  const size_t base = ((size_t)bb * LL + (size_t)ch * TCH) * HID + c;
  float h = pre[((size_t)bb * NCH + ch) * HID + c];
#pragma unroll 4
  for (int t = 0; t < TCH; ++t) {
    float at = b2f(a[base + (size_t)t * HID]);
    float bt = b2f(bsrc[base + (size_t)t * HID]);
    h = fmaf(at, h, bt);
    hout[base + (size_t)t * HID] = f2b(h);
  }
}

// ---------------- u = z + layernorm(z) -> bf16 ----------------
__global__ __launch_bounds__(256) void ln_kernel(const unsigned short* __restrict__ z,
                                                 const float* __restrict__ gam,
                                                 const float* __restrict__ bet,
                                                 unsigned short* __restrict__ u) {
  const int wave = threadIdx.x >> 6, lane = threadIdx.x & 63;
  const int row = blockIdx.x * 4 + wave;
  const unsigned short* zr = z + (size_t)row * HID + lane * 16;
  short8 z0 = *(const short8*)zr;
  short8 z1 = *(const short8*)(zr + 8);
  float x[16];
#pragma unroll
  for (int e = 0; e < 8; ++e) {
    x[e]     = b2f((unsigned short)z0[e]);
    x[8 + e] = b2f((unsigned short)z1[e]);
  }
  float s = 0.f, s2 = 0.f;
#pragma unroll
  for (int e = 0; e < 16; ++e) { s += x[e]; s2 += x[e] * x[e]; }
#pragma unroll
  for (int off = 32; off > 0; off >>= 1) {
    s += __shfl_xor(s, off, 64);
    s2 += __shfl_xor(s2, off, 64);
  }
  const float mu = s * (1.f / 1024.f);
  const float var = s2 * (1.f / 1024.f) - mu * mu;
  const float rs = rsqrtf(var + 1e-5f);
  const float* gp = gam + lane * 16;
  const float* bp = bet + lane * 16;
  short8 o0, o1;
#pragma unroll
  for (int e = 0; e < 8; ++e) {
    float v0 = x[e]     + (x[e]     - mu) * rs * gp[e]     + bp[e];
    float v1 = x[8 + e] + (x[8 + e] - mu) * rs * gp[8 + e] + bp[8 + e];
    o0[e] = (short)f2b(v0);
    o1[e] = (short)f2b(v1);
  }
  unsigned short* ur = u + (size_t)row * HID + lane * 16;
  *(short8*)ur = o0;
  *(short8*)(ur + 8) = o1;
}

// ---------------- launch ----------------
extern "C" void kernel_launch(void* const* d_in, const int* in_sizes, int n_in,
                              void* d_out, int out_size, void* d_ws, size_t ws_size,
                              hipStream_t stream) {
  if (ws_size < WS_NEEDED) return;  // diagnostic guard

  const float* emb   = (const float*)d_in[0];
  const float* Wa_w  = (const float*)d_in[1];
  const float* Wa_b  = (const float*)d_in[2];
  const float* Wb_w  = (const float*)d_in[3];
  const float* Wb_b  = (const float*)d_in[4];
  const float* Wo_w  = (const float*)d_in[5];
  const float* Wo_b  = (const float*)d_in[6];
  const float* C_w   = (const float*)d_in[7];
  const float* C_b   = (const float*)d_in[8];
  const float* ln_g  = (const float*)d_in[9];
  const float* ln_b  = (const float*)d_in[10];
  const float* f1_w  = (const float*)d_in[11];
  const float* f1_b  = (const float*)d_in[12];
  const float* f2_w  = (const float*)d_in[13];
  const float* f2_b  = (const float*)d_in[14];
  const float* p_w   = (const float*)d_in[15];
  const float* p_b   = (const float*)d_in[16];
  const float* headw = (const float*)d_in[17];

  char* ws = (char*)d_ws;
  unsigned short* bfp  = (unsigned short*)ws;
  unsigned short* uB   = (unsigned short*)(ws + OFF_U);
  unsigned short* aB   = (unsigned short*)(ws + OFF_AZ);
  unsigned short* zB   = aB;                            // a dead after scan
  unsigned short* ffnB = aB;                            // z,w dead after LN/zGEMM (64MB span)
  unsigned short* wB   = (unsigned short*)(ws + OFF_W2);
  unsigned short* hB   = (unsigned short*)(ws + OFF_H2);
  unsigned short* vB   = hB;                            // h dead after zGEMM
  unsigned short* bA   = (unsigned short*)(ws + OFF_B2);
  float* agA = (float*)(ws + OFF_AGG);
  float* agB = agA + AG_ELEMS;
  float* pre = agB + AG_ELEMS;

  convert_all<<<2048, 256, 0, stream>>>(emb, Wa_w, Wb_w, Wo_w, C_w, f1_w, f2_w, p_w, bfp);

  dim3 g8(128, 8), h32(64, 32), h8(64, 8);
  gemm_bt<0><<<g8, 256, 0, stream>>>(bfp + ELN_EMB, bfp + ELN_WA, 1024, 1024, Wa_b, nullptr, nullptr, nullptr, aB);
  gemm_bt<1><<<g8, 256, 0, stream>>>(bfp + ELN_EMB, bfp + ELN_WB, 1024, 1024, Wb_b, nullptr, nullptr, nullptr, bA);
  gemm_bt<1><<<g8, 256, 0, stream>>>(bfp + ELN_EMB, bfp + ELN_WO, 1024, 1024, Wo_b, nullptr, nullptr, nullptr, wB);

  scan_p1<<<BB * NCH * 4, 256, 0, stream>>>(aB, bA, agA, agB);
  scan_p2<<<16, 256, 0, stream>>>(agA, agB, pre);
  scan_p3<<<BB * NCH * 4, 256, 0, stream>>>(aB, bA, pre, hB);

  gemm_bt<2><<<g8, 256, 0, stream>>>(hB, bfp + ELN_CW, 1024, 1024, C_b, wB, headw, nullptr, zB);
  ln_kernel<<<4096, 256, 0, stream>>>(zB, ln_g, ln_b, uB);

  // FFN in two M-halves so ffn fits in 64MB (regions AZ+W2)
  for (int half = 0; half < 2; ++half) {
    const size_t ro = (size_t)half * 8192 * 1024;
    gemm_bt<3><<<h32, 256, 0, stream>>>(uB + ro, bfp + ELN_F1, 1024, 4096, f1_b, nullptr, nullptr, nullptr, ffnB);
    gemm_bt<4><<<h8, 256, 0, stream>>>(ffnB, bfp + ELN_F2, 4096, 1024, f2_b, uB + ro, nullptr, nullptr, vB + ro);
  }

  gemm_bt<5><<<g8, 256, 0, stream>>>(vB, bfp + ELN_PW, 1024, 1024, p_b, nullptr, nullptr, (float*)d_out, nullptr);
}

// Round 6
// 664.027 us; speedup vs baseline: 1.2297x; 1.2297x over previous
//
#include <hip/hip_runtime.h>
#include <hip/hip_bf16.h>

typedef __attribute__((ext_vector_type(8))) short short8;
typedef __attribute__((ext_vector_type(4))) float f32x4;

#define DEVI static __device__ __forceinline__

constexpr int HID = 1024;
constexpr int BB = 4, LL = 4096;
constexpr int MROWS = BB * LL;   // 16384
constexpr int NCH = 64, TCH = 64;

// ---------------- ws layout ----------------
// bf16 pool elems
constexpr size_t ELN_EMB  = 0;                  // 16,777,216
constexpr size_t ELN_WABO = 16777216;           // packed Wa|Wb|Wo rows: 3,145,728
constexpr size_t ELN_CW   = 19922944;
constexpr size_t ELN_F1   = 20971520;
constexpr size_t ELN_F2   = 25165824;
constexpr size_t ELN_PW   = 29360128;
constexpr size_t ELN_END  = 30408704;
constexpr size_t POOL_BYTES = ELN_END * 2;      // 60,817,408

constexpr size_t OFF_ABW = POOL_BYTES;                       // abw [M][3072] bf16 = 96MB; ffn spans ABW+H = 128MB
constexpr size_t OFF_H   = OFF_ABW + (size_t)MROWS*3072*2;   // h [M][1024] bf16 = 32MB
constexpr size_t OFF_U   = OFF_H  + (size_t)MROWS*1024*2;    // u bf16 = 32MB (v in-place later)
constexpr size_t OFF_AGG = OFF_U  + (size_t)MROWS*1024*2;    // scan aggregates 3MB
constexpr size_t AG_ELEMS = (size_t)BB * NCH * HID;
constexpr size_t WS_NEEDED = OFF_AGG + AG_ELEMS * 4 * 3;     // 231,735,296 (same as proven)

// ---------------- helpers ----------------
DEVI unsigned short f2b(float x) {
  unsigned u = __float_as_uint(x);
  return (unsigned short)((u + 0x7fffu + ((u >> 16) & 1u)) >> 16);
}
DEVI float b2f(unsigned short u) { return __uint_as_float((unsigned)u << 16); }

DEVI float fast_tanh(float y) {          // exp2-based, clamped (no inf/nan)
  y = fminf(fmaxf(y, -10.f), 10.f);
  float e = __expf(2.f * y);
  return (e - 1.f) / (e + 1.f);
}
DEVI float gelu_fast(float x) {          // tanh-form gelu, |err| <= ~3e-4
  float t = 0.7978845608028654f * (x + 0.044715f * x * x * x);
  return 0.5f * x * (1.f + fast_tanh(t));
}

DEVI void gload_lds16(const unsigned short* g, unsigned short* l) {
  __builtin_amdgcn_global_load_lds(
      (const __attribute__((address_space(1))) void*)g,
      (__attribute__((address_space(3))) void*)l, 16, 0, 0);
}
DEVI void sbar() { __builtin_amdgcn_s_barrier(); }
DEVI void vmwait0() { asm volatile("s_waitcnt vmcnt(0)" ::: "memory"); }

// ---------------- f32 -> bf16 conversion: emb + packed weights ----------------
constexpr long CH_EMB = 16777216 / 8;
constexpr long CH_W   = 1048576 / 8;
constexpr long CH_F   = 4194304 / 8;
constexpr long SEG1 = CH_EMB;
constexpr long SEG2 = SEG1 + CH_W;   // wa -> WABO+0
constexpr long SEG3 = SEG2 + CH_W;   // wb -> WABO+1M
constexpr long SEG4 = SEG3 + CH_W;   // wo -> WABO+2M
constexpr long SEG5 = SEG4 + CH_W;   // cw
constexpr long SEG6 = SEG5 + CH_F;   // f1
constexpr long SEG7 = SEG6 + CH_F;   // f2
constexpr long SEG8 = SEG7 + CH_W;   // pw

__global__ __launch_bounds__(256) void convert_all(
    const float* __restrict__ emb, const float* __restrict__ wa,
    const float* __restrict__ wb,  const float* __restrict__ wo,
    const float* __restrict__ cw,  const float* __restrict__ f1,
    const float* __restrict__ f2,  const float* __restrict__ pw,
    unsigned short* __restrict__ dst) {
  const long stride = (long)gridDim.x * blockDim.x;
  for (long ck = (long)blockIdx.x * blockDim.x + threadIdx.x; ck < SEG8; ck += stride) {
    const float* s; size_t d;
    if (ck < SEG1)      { s = emb + (size_t)ck * 8;        d = ELN_EMB + (size_t)ck * 8; }
    else if (ck < SEG2) { s = wa + (size_t)(ck-SEG1) * 8;  d = ELN_WABO + (size_t)(ck-SEG1) * 8; }
    else if (ck < SEG3) { s = wb + (size_t)(ck-SEG2) * 8;  d = ELN_WABO + 1048576 + (size_t)(ck-SEG2) * 8; }
    else if (ck < SEG4) { s = wo + (size_t)(ck-SEG3) * 8;  d = ELN_WABO + 2097152 + (size_t)(ck-SEG3) * 8; }
    else if (ck < SEG5) { s = cw + (size_t)(ck-SEG4) * 8;  d = ELN_CW + (size_t)(ck-SEG4) * 8; }
    else if (ck < SEG6) { s = f1 + (size_t)(ck-SEG5) * 8;  d = ELN_F1 + (size_t)(ck-SEG5) * 8; }
    else if (ck < SEG7) { s = f2 + (size_t)(ck-SEG6) * 8;  d = ELN_F2 + (size_t)(ck-SEG6) * 8; }
    else                { s = pw + (size_t)(ck-SEG7) * 8;  d = ELN_PW + (size_t)(ck-SEG7) * 8; }
    float4 x = *(const float4*)s;
    float4 y = *(const float4*)(s + 4);
    short8 o;
    o[0]=(short)f2b(x.x); o[1]=(short)f2b(x.y); o[2]=(short)f2b(x.z); o[3]=(short)f2b(x.w);
    o[4]=(short)f2b(y.x); o[5]=(short)f2b(y.y); o[6]=(short)f2b(y.z); o[7]=(short)f2b(y.w);
    *(short8*)(dst + d) = o;
  }
}

// ---------------- 256x256 BK=64 pipelined GEMM: C = A(MxK) * W(NxK)^T ----------
// 8 waves (2Mx4N), per-wave 128x64 out, acc[8][4] f32x4. LDS 128KB dbuf.
// Per K-tile: 4 sub-phases (mh x ks), 16 MFMA each; stage next tile at phase a;
// ONE vmcnt(0) per tile (waits loads issued ~4 phases earlier); raw s_barrier.
// EPI: 0 abw (tanh cols<1024) | 1 z=hw*(acc+b+w) | 2 gelu | 3 acc+b+u in-place | 4 +b->f32
template <int EPI>
__global__ __launch_bounds__(512) void gemm256(
    const unsigned short* __restrict__ A, const unsigned short* __restrict__ Bw,
    int K, int NT, int ldo, int addld,
    const float* __restrict__ biasA, const float* __restrict__ biasB,
    const float* __restrict__ biasW,
    const unsigned short* __restrict__ addB, const float* __restrict__ hw,
    float* __restrict__ outF, unsigned short* __restrict__ outB) {
  __shared__ alignas(16) unsigned short lds[2][2][16384];  // [buf][A/B][256*64]
  const int tid = threadIdx.x;
  const int lane = tid & 63, wave = tid >> 6;
  const int wr = wave >> 2, wc = wave & 3;
  const int arow0 = blockIdx.x * 256, bcol0 = blockIdx.y * 256;
  const int rowb = tid >> 3, kc = (tid & 7) * 8;
  const unsigned short* Ag = A + (size_t)(arow0 + rowb) * K + kc;
  const unsigned short* Bg = Bw + (size_t)(bcol0 + rowb) * K + kc;
  f32x4 acc[8][4] = {};
  const int fm = lane & 15, fg = lane >> 4;

#define STAGE8(p, kt) do { const int k0_ = (kt) * 64;                              \
    _Pragma("unroll") for (int l = 0; l < 4; ++l) {                                \
      gload_lds16(Ag + (size_t)(64 * l) * K + k0_, &lds[p][0][tid * 8 + 4096 * l]);\
      gload_lds16(Bg + (size_t)(64 * l) * K + k0_, &lds[p][1][tid * 8 + 4096 * l]);\
    } } while (0)

  STAGE8(0, 0);
  vmwait0();
  sbar();

  for (int t = 0; t < NT; ++t) {
    const int p = t & 1;
    if (t + 1 < NT) STAGE8(p ^ 1, t + 1);
    const unsigned short* LA = &lds[p][0][(wr * 128 + fm) * 64 + fg * 8];
    const unsigned short* LB = &lds[p][1][(wc * 64 + fm) * 64 + fg * 8];
    short8 af[4], bf[4];
    // phase a: mh0, ks0  (8 ds_read + stage issued above)
#pragma unroll
    for (int n = 0; n < 4; ++n) bf[n] = *(const short8*)(LB + n * 16 * 64);
#pragma unroll
    for (int m = 0; m < 4; ++m) af[m] = *(const short8*)(LA + m * 16 * 64);
    __builtin_amdgcn_s_setprio(1);
#pragma unroll
    for (int m = 0; m < 4; ++m)
#pragma unroll
      for (int n = 0; n < 4; ++n)
        acc[m][n] = __builtin_amdgcn_mfma_f32_16x16x32_bf16(af[m], bf[n], acc[m][n], 0, 0, 0);
    __builtin_amdgcn_s_setprio(0);
    sbar();
    // phase b: mh1, ks0 (4 ds_read, B reused)
#pragma unroll
    for (int m = 0; m < 4; ++m) af[m] = *(const short8*)(LA + (64 + m * 16) * 64);
    __builtin_amdgcn_s_setprio(1);
#pragma unroll
    for (int m = 0; m < 4; ++m)
#pragma unroll
      for (int n = 0; n < 4; ++n)
        acc[4 + m][n] = __builtin_amdgcn_mfma_f32_16x16x32_bf16(af[m], bf[n], acc[4 + m][n], 0, 0, 0);
    __builtin_amdgcn_s_setprio(0);
    sbar();
    // phase c: mh0, ks1 (8 ds_read)
#pragma unroll
    for (int n = 0; n < 4; ++n) bf[n] = *(const short8*)(LB + n * 16 * 64 + 32);
#pragma unroll
    for (int m = 0; m < 4; ++m) af[m] = *(const short8*)(LA + m * 16 * 64 + 32);
    __builtin_amdgcn_s_setprio(1);
#pragma unroll
    for (int m = 0; m < 4; ++m)
#pragma unroll
      for (int n = 0; n < 4; ++n)
        acc[m][n] = __builtin_amdgcn_mfma_f32_16x16x32_bf16(af[m], bf[n], acc[m][n], 0, 0, 0);
    __builtin_amdgcn_s_setprio(0);
    sbar();
    // phase d: mh1, ks1 (4 ds_read)
#pragma unroll
    for (int m = 0; m < 4; ++m) af[m] = *(const short8*)(LA + (64 + m * 16) * 64 + 32);
    __builtin_amdgcn_s_setprio(1);
#pragma unroll
    for (int m = 0; m < 4; ++m)
#pragma unroll
      for (int n = 0; n < 4; ++n)
        acc[4 + m][n] = __builtin_amdgcn_mfma_f32_16x16x32_bf16(af[m], bf[n], acc[4 + m][n], 0, 0, 0);
    __builtin_amdgcn_s_setprio(0);
    vmwait0();                      // next tile resident (issued at phase a)
    sbar();
    __builtin_amdgcn_sched_barrier(0);  // no cross-tile motion
  }
#undef STAGE8

  // epilogue: D row = (lane>>4)*4 + reg, col = lane&15 [m89-verified]
  const int crow = (lane >> 4) * 4, ccol = lane & 15;
#pragma unroll
  for (int m = 0; m < 8; ++m) {
    const int row0 = arow0 + wr * 128 + (m >> 2) * 64 + (m & 3) * 16 + crow;
#pragma unroll
    for (int n = 0; n < 4; ++n) {
      const int col = bcol0 + wc * 64 + n * 16 + ccol;
#pragma unroll
      for (int r = 0; r < 4; ++r) {
        const size_t orow = (size_t)(row0 + r);
        float x = acc[m][n][r];
        if constexpr (EPI == 0) {
          const int cb = col >> 10;
          const float* bp = (cb == 0) ? biasA : (cb == 1 ? biasB : biasW);
          x += bp[col & 1023];
          if (cb == 0) x = fast_tanh(x);
          outB[orow * 3072 + col] = f2b(x);
        } else if constexpr (EPI == 1) {
          x += biasA[col] + b2f(addB[orow * (size_t)addld + col]);
          x *= hw[col >> 6];
          outB[orow * (size_t)ldo + col] = f2b(x);
        } else if constexpr (EPI == 2) {
          x += biasA[col];
          outB[orow * (size_t)ldo + col] = f2b(gelu_fast(x));
        } else if constexpr (EPI == 3) {
          x += biasA[col] + b2f(addB[orow * (size_t)addld + col]);
          outB[orow * (size_t)ldo + col] = f2b(x);
        } else {
          outF[orow * (size_t)ldo + col] = x + biasA[col];
        }
      }
    }
  }
}

// ---------------- chunked affine scan over abw layout [M][3072] ----------------
__global__ __launch_bounds__(256) void scan_p1(const unsigned short* __restrict__ abw,
                                               float* __restrict__ agA,
                                               float* __restrict__ agB) {
  const int idx = blockIdx.x;
  const int cg = idx & 3, ch = (idx >> 2) & (NCH - 1), bb = idx >> 8;
  const int c = cg * 256 + threadIdx.x;
  const size_t base = ((size_t)bb * LL + (size_t)ch * TCH) * 3072 + c;
  float A = 1.f, Bg = 0.f;
#pragma unroll 4
  for (int t = 0; t < TCH; ++t) {
    float at = b2f(abw[base + (size_t)t * 3072]);
    float bt = b2f(abw[base + (size_t)t * 3072 + 1024]);
    Bg = fmaf(at, Bg, bt);
    A *= at;
  }
  const size_t o = ((size_t)bb * NCH + ch) * HID + c;
  agA[o] = A;
  agB[o] = Bg;
}

__global__ __launch_bounds__(256) void scan_p2(const float* __restrict__ agA,
                                               const float* __restrict__ agB,
                                               float* __restrict__ pre) {
  const int gid = blockIdx.x * 256 + threadIdx.x;
  const int bb = gid >> 10, c = gid & 1023;
  float h = 0.f;
  for (int ch = 0; ch < NCH; ++ch) {
    const size_t o = ((size_t)bb * NCH + ch) * HID + c;
    pre[o] = h;
    h = fmaf(agA[o], h, agB[o]);
  }
}

__global__ __launch_bounds__(256) void scan_p3(const unsigned short* __restrict__ abw,
                                               const float* __restrict__ pre,
                                               unsigned short* __restrict__ hout) {
  const int idx = blockIdx.x;
  const int cg = idx & 3, ch = (idx >> 2) & (NCH - 1), bb = idx >> 8;
  const int c = cg * 256 + threadIdx.x;
  const size_t base = ((size_t)bb * LL + (size_t)ch * TCH) * 3072 + c;
  const size_t hbase = ((size_t)bb * LL + (size_t)ch * TCH) * HID + c;
  float h = pre[((size_t)bb * NCH + ch) * HID + c];
#pragma unroll 4
  for (int t = 0; t < TCH; ++t) {
    float at = b2f(abw[base + (size_t)t * 3072]);
    float bt = b2f(abw[base + (size_t)t * 3072 + 1024]);
    h = fmaf(at, h, bt);
    hout[hbase + (size_t)t * HID] = f2b(h);
  }
}

// ---------------- u = z + layernorm(z); z in abw[.,0..1023] ----------------
__global__ __launch_bounds__(256) void ln_kernel(const unsigned short* __restrict__ abw,
                                                 const float* __restrict__ gam,
                                                 const float* __restrict__ bet,
                                                 unsigned short* __restrict__ u) {
  const int wave = threadIdx.x >> 6, lane = threadIdx.x & 63;
  const int row = blockIdx.x * 4 + wave;
  const unsigned short* zr = abw + (size_t)row * 3072 + lane * 16;
  short8 z0 = *(const short8*)zr;
  short8 z1 = *(const short8*)(zr + 8);
  float x[16];
#pragma unroll
  for (int e = 0; e < 8; ++e) {
    x[e]     = b2f((unsigned short)z0[e]);
    x[8 + e] = b2f((unsigned short)z1[e]);
  }
  float s = 0.f, s2 = 0.f;
#pragma unroll
  for (int e = 0; e < 16; ++e) { s += x[e]; s2 += x[e] * x[e]; }
#pragma unroll
  for (int off = 32; off > 0; off >>= 1) {
    s += __shfl_xor(s, off, 64);
    s2 += __shfl_xor(s2, off, 64);
  }
  const float mu = s * (1.f / 1024.f);
  const float var = s2 * (1.f / 1024.f) - mu * mu;
  const float rs = rsqrtf(var + 1e-5f);
  const float* gp = gam + lane * 16;
  const float* bp = bet + lane * 16;
  short8 o0, o1;
#pragma unroll
  for (int e = 0; e < 8; ++e) {
    float v0 = x[e]     + (x[e]     - mu) * rs * gp[e]     + bp[e];
    float v1 = x[8 + e] + (x[8 + e] - mu) * rs * gp[8 + e] + bp[8 + e];
    o0[e] = (short)f2b(v0);
    o1[e] = (short)f2b(v1);
  }
  unsigned short* ur = u + (size_t)row * HID + lane * 16;
  *(short8*)ur = o0;
  *(short8*)(ur + 8) = o1;
}

// ---------------- launch ----------------
extern "C" void kernel_launch(void* const* d_in, const int* in_sizes, int n_in,
                              void* d_out, int out_size, void* d_ws, size_t ws_size,
                              hipStream_t stream) {
  if (ws_size < WS_NEEDED) return;

  const float* emb   = (const float*)d_in[0];
  const float* Wa_w  = (const float*)d_in[1];
  const float* Wa_b  = (const float*)d_in[2];
  const float* Wb_w  = (const float*)d_in[3];
  const float* Wb_b  = (const float*)d_in[4];
  const float* Wo_w  = (const float*)d_in[5];
  const float* Wo_b  = (const float*)d_in[6];
  const float* C_w   = (const float*)d_in[7];
  const float* C_b   = (const float*)d_in[8];
  const float* ln_g  = (const float*)d_in[9];
  const float* ln_b  = (const float*)d_in[10];
  const float* f1_w  = (const float*)d_in[11];
  const float* f1_b  = (const float*)d_in[12];
  const float* f2_w  = (const float*)d_in[13];
  const float* f2_b  = (const float*)d_in[14];
  const float* p_w   = (const float*)d_in[15];
  const float* p_b   = (const float*)d_in[16];
  const float* headw = (const float*)d_in[17];

  char* ws = (char*)d_ws;
  unsigned short* bfp  = (unsigned short*)ws;
  unsigned short* abwB = (unsigned short*)(ws + OFF_ABW);
  unsigned short* hB   = (unsigned short*)(ws + OFF_H);
  unsigned short* uB   = (unsigned short*)(ws + OFF_U);
  unsigned short* ffnB = abwB;                  // ffn [M][4096] spans abw+h (128MB)
  float* agA = (float*)(ws + OFF_AGG);
  float* agB = agA + AG_ELEMS;
  float* pre = agB + AG_ELEMS;

  convert_all<<<2048, 256, 0, stream>>>(emb, Wa_w, Wb_w, Wo_w, C_w, f1_w, f2_w, p_w, bfp);

  // abw = [tanh(emb@Wa^T+ba) | emb@Wb^T+bb | emb@Wo^T+bo]   (M=16384, N=3072, K=1024)
  gemm256<0><<<dim3(64, 12), 512, 0, stream>>>(
      bfp + ELN_EMB, bfp + ELN_WABO, 1024, 16, 3072, 0,
      Wa_b, Wb_b, Wo_b, nullptr, nullptr, nullptr, abwB);

  scan_p1<<<BB * NCH * 4, 256, 0, stream>>>(abwB, agA, agB);
  scan_p2<<<16, 256, 0, stream>>>(agA, agB, pre);
  scan_p3<<<BB * NCH * 4, 256, 0, stream>>>(abwB, pre, hB);

  // z = hw * (h@C^T + cb + w)  -> abw[.,0..1023]   (addB = w slice at +2048, ld 3072)
  gemm256<1><<<dim3(64, 4), 512, 0, stream>>>(
      hB, bfp + ELN_CW, 1024, 16, 3072, 3072,
      C_b, nullptr, nullptr, abwB + 2048, headw, nullptr, abwB);

  ln_kernel<<<4096, 256, 0, stream>>>(abwB, ln_g, ln_b, uB);

  // ffn = gelu(u@f1^T + b1)   (M=16384, N=4096, K=1024)
  gemm256<2><<<dim3(64, 16), 512, 0, stream>>>(
      uB, bfp + ELN_F1, 1024, 16, 4096, 0,
      f1_b, nullptr, nullptr, nullptr, nullptr, nullptr, ffnB);

  // v = ffn@f2^T + b2 + u  (in-place over u)   (K=4096, NT=64)
  gemm256<3><<<dim3(64, 4), 512, 0, stream>>>(
      ffnB, bfp + ELN_F2, 4096, 64, 1024, 1024,
      f2_b, nullptr, nullptr, uB, nullptr, nullptr, uB);

  // out = v@p^T + pb  (f32)
  gemm256<4><<<dim3(64, 4), 512, 0, stream>>>(
      uB, bfp + ELN_PW, 1024, 16, 1024, 0,
      p_b, nullptr, nullptr, nullptr, nullptr, (float*)d_out, nullptr);
}

// Round 7
// 559.397 us; speedup vs baseline: 1.4597x; 1.1870x over previous
//
#include <hip/hip_runtime.h>
#include <hip/hip_bf16.h>

typedef __attribute__((ext_vector_type(8))) short short8;
typedef __attribute__((ext_vector_type(4))) float f32x4;

#define DEVI static __device__ __forceinline__

constexpr int HID = 1024;
constexpr int BB = 4, LL = 4096;
constexpr int MROWS = BB * LL;   // 16384
constexpr int NCH = 64, TCH = 64;

// ---------------- ws layout ----------------
constexpr size_t ELN_EMB  = 0;                  // 16,777,216
constexpr size_t ELN_WABO = 16777216;           // packed Wa|Wb|Wo rows: 3,145,728
constexpr size_t ELN_CW   = 19922944;
constexpr size_t ELN_F1   = 20971520;
constexpr size_t ELN_F2   = 25165824;
constexpr size_t ELN_PW   = 29360128;
constexpr size_t ELN_END  = 30408704;
constexpr size_t POOL_BYTES = ELN_END * 2;      // 60,817,408

constexpr size_t OFF_ABW = POOL_BYTES;                       // abw [M][3072] bf16 = 96MB; ffn spans ABW+H
constexpr size_t OFF_H   = OFF_ABW + (size_t)MROWS*3072*2;   // h [M][1024] bf16 = 32MB
constexpr size_t OFF_U   = OFF_H  + (size_t)MROWS*1024*2;    // u bf16 = 32MB (v in-place later)
constexpr size_t OFF_AGG = OFF_U  + (size_t)MROWS*1024*2;    // scan aggregates 3MB
constexpr size_t AG_ELEMS = (size_t)BB * NCH * HID;
constexpr size_t WS_NEEDED = OFF_AGG + AG_ELEMS * 4 * 3;     // 231,735,296 (proven fit)

// ---------------- helpers ----------------
DEVI unsigned short f2b(float x) {
  unsigned u = __float_as_uint(x);
  return (unsigned short)((u + 0x7fffu + ((u >> 16) & 1u)) >> 16);
}
DEVI float b2f(unsigned short u) { return __uint_as_float((unsigned)u << 16); }

DEVI float fast_tanh(float y) {
  y = fminf(fmaxf(y, -10.f), 10.f);
  float e = __expf(2.f * y);
  return (e - 1.f) / (e + 1.f);
}
DEVI float gelu_fast(float x) {
  float t = 0.7978845608028654f * (x + 0.044715f * x * x * x);
  return 0.5f * x * (1.f + fast_tanh(t));
}

DEVI void gload_lds16(const unsigned short* g, unsigned short* l) {
  __builtin_amdgcn_global_load_lds(
      (const __attribute__((address_space(1))) void*)g,
      (__attribute__((address_space(3))) void*)l, 16, 0, 0);
}
DEVI void sbar() { __builtin_amdgcn_s_barrier(); }
DEVI void vmwait0() { asm volatile("s_waitcnt vmcnt(0)" ::: "memory"); }

// ---------------- f32 -> bf16 conversion: emb + packed weights ----------------
constexpr long CH_EMB = 16777216 / 8;
constexpr long CH_W   = 1048576 / 8;
constexpr long CH_F   = 4194304 / 8;
constexpr long SEG1 = CH_EMB;
constexpr long SEG2 = SEG1 + CH_W;
constexpr long SEG3 = SEG2 + CH_W;
constexpr long SEG4 = SEG3 + CH_W;
constexpr long SEG5 = SEG4 + CH_W;
constexpr long SEG6 = SEG5 + CH_F;
constexpr long SEG7 = SEG6 + CH_F;
constexpr long SEG8 = SEG7 + CH_W;

__global__ __launch_bounds__(256) void convert_all(
    const float* __restrict__ emb, const float* __restrict__ wa,
    const float* __restrict__ wb,  const float* __restrict__ wo,
    const float* __restrict__ cw,  const float* __restrict__ f1,
    const float* __restrict__ f2,  const float* __restrict__ pw,
    unsigned short* __restrict__ dst) {
  const long stride = (long)gridDim.x * blockDim.x;
  for (long ck = (long)blockIdx.x * blockDim.x + threadIdx.x; ck < SEG8; ck += stride) {
    const float* s; size_t d;
    if (ck < SEG1)      { s = emb + (size_t)ck * 8;        d = ELN_EMB + (size_t)ck * 8; }
    else if (ck < SEG2) { s = wa + (size_t)(ck-SEG1) * 8;  d = ELN_WABO + (size_t)(ck-SEG1) * 8; }
    else if (ck < SEG3) { s = wb + (size_t)(ck-SEG2) * 8;  d = ELN_WABO + 1048576 + (size_t)(ck-SEG2) * 8; }
    else if (ck < SEG4) { s = wo + (size_t)(ck-SEG3) * 8;  d = ELN_WABO + 2097152 + (size_t)(ck-SEG3) * 8; }
    else if (ck < SEG5) { s = cw + (size_t)(ck-SEG4) * 8;  d = ELN_CW + (size_t)(ck-SEG4) * 8; }
    else if (ck < SEG6) { s = f1 + (size_t)(ck-SEG5) * 8;  d = ELN_F1 + (size_t)(ck-SEG5) * 8; }
    else if (ck < SEG7) { s = f2 + (size_t)(ck-SEG6) * 8;  d = ELN_F2 + (size_t)(ck-SEG6) * 8; }
    else                { s = pw + (size_t)(ck-SEG7) * 8;  d = ELN_PW + (size_t)(ck-SEG7) * 8; }
    float4 x = *(const float4*)s;
    float4 y = *(const float4*)(s + 4);
    short8 o;
    o[0]=(short)f2b(x.x); o[1]=(short)f2b(x.y); o[2]=(short)f2b(x.z); o[3]=(short)f2b(x.w);
    o[4]=(short)f2b(y.x); o[5]=(short)f2b(y.y); o[6]=(short)f2b(y.z); o[7]=(short)f2b(y.w);
    *(short8*)(dst + d) = o;
  }
}

// ---------------- 256x256 BK=64 pipelined GEMM, T2-swizzled LDS ----------------
// LDS(row, slot s) holds global col-block (s ^ (row&7)); write side realizes this
// by pre-swizzling the per-lane GLOBAL source (kc), read side XORs the slot.
// EPI: 0 abw (tanh cols<1024) | 1 z=hw*(acc+b+w) | 2 gelu | 3 acc+b+u | 4 +b->f32
template <int EPI>
__global__ __launch_bounds__(512) void gemm256(
    const unsigned short* __restrict__ A, const unsigned short* __restrict__ Bw,
    int K, int NT, int ldo, int addld,
    const float* __restrict__ biasA, const float* __restrict__ biasB,
    const float* __restrict__ biasW,
    const unsigned short* __restrict__ addB, const float* __restrict__ hw,
    float* __restrict__ outF, unsigned short* __restrict__ outB) {
  __shared__ alignas(16) unsigned short lds[2][2][16384];  // [buf][A/B][256*64]
  const int tid = threadIdx.x;
  const int lane = tid & 63, wave = tid >> 6;
  const int wr = wave >> 2, wc = wave & 3;
  const int arow0 = blockIdx.x * 256, bcol0 = blockIdx.y * 256;
  const int rowb = tid >> 3;
  const int kc = (((tid & 7) ^ (rowb & 7)) * 8);     // T2: pre-swizzled source slot
  const unsigned short* Ag = A + (size_t)(arow0 + rowb) * K + kc;
  const unsigned short* Bg = Bw + (size_t)(bcol0 + rowb) * K + kc;
  f32x4 acc[8][4] = {};
  const int fm = lane & 15, fg = lane >> 4;
  const int sw0 = ((fg ^ (fm & 7)) * 8);             // T2: ks0 read slot
  const int sw1 = (((fg + 4) ^ (fm & 7)) * 8);       // T2: ks1 read slot

#define STAGE8(p, kt) do { const int k0_ = (kt) * 64;                              \
    _Pragma("unroll") for (int l = 0; l < 4; ++l) {                                \
      gload_lds16(Ag + (size_t)(64 * l) * K + k0_, &lds[p][0][tid * 8 + 4096 * l]);\
      gload_lds16(Bg + (size_t)(64 * l) * K + k0_, &lds[p][1][tid * 8 + 4096 * l]);\
    } } while (0)

  STAGE8(0, 0);
  vmwait0();
  sbar();

  for (int t = 0; t < NT; ++t) {
    const int p = t & 1;
    if (t + 1 < NT) STAGE8(p ^ 1, t + 1);
    const unsigned short* LA = &lds[p][0][(wr * 128 + fm) * 64];
    const unsigned short* LB = &lds[p][1][(wc * 64 + fm) * 64];
    short8 af[4], bf[4];
    // phase a: mh0, ks0
#pragma unroll
    for (int n = 0; n < 4; ++n) bf[n] = *(const short8*)(LB + n * 16 * 64 + sw0);
#pragma unroll
    for (int m = 0; m < 4; ++m) af[m] = *(const short8*)(LA + m * 16 * 64 + sw0);
    __builtin_amdgcn_s_setprio(1);
#pragma unroll
    for (int m = 0; m < 4; ++m)
#pragma unroll
      for (int n = 0; n < 4; ++n)
        acc[m][n] = __builtin_amdgcn_mfma_f32_16x16x32_bf16(af[m], bf[n], acc[m][n], 0, 0, 0);
    __builtin_amdgcn_s_setprio(0);
    sbar();
    // phase b: mh1, ks0 (B reused)
#pragma unroll
    for (int m = 0; m < 4; ++m) af[m] = *(const short8*)(LA + (64 + m * 16) * 64 + sw0);
    __builtin_amdgcn_s_setprio(1);
#pragma unroll
    for (int m = 0; m < 4; ++m)
#pragma unroll
      for (int n = 0; n < 4; ++n)
        acc[4 + m][n] = __builtin_amdgcn_mfma_f32_16x16x32_bf16(af[m], bf[n], acc[4 + m][n], 0, 0, 0);
    __builtin_amdgcn_s_setprio(0);
    sbar();
    // phase c: mh0, ks1
#pragma unroll
    for (int n = 0; n < 4; ++n) bf[n] = *(const short8*)(LB + n * 16 * 64 + sw1);
#pragma unroll
    for (int m = 0; m < 4; ++m) af[m] = *(const short8*)(LA + m * 16 * 64 + sw1);
    __builtin_amdgcn_s_setprio(1);
#pragma unroll
    for (int m = 0; m < 4; ++m)
#pragma unroll
      for (int n = 0; n < 4; ++n)
        acc[m][n] = __builtin_amdgcn_mfma_f32_16x16x32_bf16(af[m], bf[n], acc[m][n], 0, 0, 0);
    __builtin_amdgcn_s_setprio(0);
    sbar();
    // phase d: mh1, ks1
#pragma unroll
    for (int m = 0; m < 4; ++m) af[m] = *(const short8*)(LA + (64 + m * 16) * 64 + sw1);
    __builtin_amdgcn_s_setprio(1);
#pragma unroll
    for (int m = 0; m < 4; ++m)
#pragma unroll
      for (int n = 0; n < 4; ++n)
        acc[4 + m][n] = __builtin_amdgcn_mfma_f32_16x16x32_bf16(af[m], bf[n], acc[4 + m][n], 0, 0, 0);
    __builtin_amdgcn_s_setprio(0);
    vmwait0();                      // next tile resident (issued at phase a)
    sbar();
    __builtin_amdgcn_sched_barrier(0);
  }
#undef STAGE8

  // epilogue: D row = (lane>>4)*4 + reg, col = lane&15 [m89-verified]
  const int crow = (lane >> 4) * 4, ccol = lane & 15;
#pragma unroll
  for (int m = 0; m < 8; ++m) {
    const int row0 = arow0 + wr * 128 + (m >> 2) * 64 + (m & 3) * 16 + crow;
#pragma unroll
    for (int n = 0; n < 4; ++n) {
      const int col = bcol0 + wc * 64 + n * 16 + ccol;
#pragma unroll
      for (int r = 0; r < 4; ++r) {
        const size_t orow = (size_t)(row0 + r);
        float x = acc[m][n][r];
        if constexpr (EPI == 0) {
          const int cb = col >> 10;
          const float* bp = (cb == 0) ? biasA : (cb == 1 ? biasB : biasW);
          x += bp[col & 1023];
          if (cb == 0) x = fast_tanh(x);
          outB[orow * 3072 + col] = f2b(x);
        } else if constexpr (EPI == 1) {
          x += biasA[col] + b2f(addB[orow * (size_t)addld + col]);
          x *= hw[col >> 6];
          outB[orow * (size_t)ldo + col] = f2b(x);
        } else if constexpr (EPI == 2) {
          x += biasA[col];
          outB[orow * (size_t)ldo + col] = f2b(gelu_fast(x));
        } else if constexpr (EPI == 3) {
          x += biasA[col] + b2f(addB[orow * (size_t)addld + col]);
          outB[orow * (size_t)ldo + col] = f2b(x);
        } else {
          outF[orow * (size_t)ldo + col] = x + biasA[col];
        }
      }
    }
  }
}

// ---------------- chunked affine scan over abw layout [M][3072] ----------------
__global__ __launch_bounds__(256) void scan_p1(const unsigned short* __restrict__ abw,
                                               float* __restrict__ agA,
                                               float* __restrict__ agB) {
  const int idx = blockIdx.x;
  const int cg = idx & 3, ch = (idx >> 2) & (NCH - 1), bb = idx >> 8;
  const int c = cg * 256 + threadIdx.x;
  const size_t base = ((size_t)bb * LL + (size_t)ch * TCH) * 3072 + c;
  float A = 1.f, Bg = 0.f;
#pragma unroll 4
  for (int t = 0; t < TCH; ++t) {
    float at = b2f(abw[base + (size_t)t * 3072]);
    float bt = b2f(abw[base + (size_t)t * 3072 + 1024]);
    Bg = fmaf(at, Bg, bt);
    A *= at;
  }
  const size_t o = ((size_t)bb * NCH + ch) * HID + c;
  agA[o] = A;
  agB[o] = Bg;
}

__global__ __launch_bounds__(256) void scan_p2(const float* __restrict__ agA,
                                               const float* __restrict__ agB,
                                               float* __restrict__ pre) {
  const int gid = blockIdx.x * 256 + threadIdx.x;
  const int bb = gid >> 10, c = gid & 1023;
  float h = 0.f;
  for (int ch = 0; ch < NCH; ++ch) {
    const size_t o = ((size_t)bb * NCH + ch) * HID + c;
    pre[o] = h;
    h = fmaf(agA[o], h, agB[o]);
  }
}

__global__ __launch_bounds__(256) void scan_p3(const unsigned short* __restrict__ abw,
                                               const float* __restrict__ pre,
                                               unsigned short* __restrict__ hout) {
  const int idx = blockIdx.x;
  const int cg = idx & 3, ch = (idx >> 2) & (NCH - 1), bb = idx >> 8;
  const int c = cg * 256 + threadIdx.x;
  const size_t base = ((size_t)bb * LL + (size_t)ch * TCH) * 3072 + c;
  const size_t hbase = ((size_t)bb * LL + (size_t)ch * TCH) * HID + c;
  float h = pre[((size_t)bb * NCH + ch) * HID + c];
#pragma unroll 4
  for (int t = 0; t < TCH; ++t) {
    float at = b2f(abw[base + (size_t)t * 3072]);
    float bt = b2f(abw[base + (size_t)t * 3072 + 1024]);
    h = fmaf(at, h, bt);
    hout[hbase + (size_t)t * HID] = f2b(h);
  }
}

// ---------------- u = z + layernorm(z); z in abw[.,0..1023] ----------------
__global__ __launch_bounds__(256) void ln_kernel(const unsigned short* __restrict__ abw,
                                                 const float* __restrict__ gam,
                                                 const float* __restrict__ bet,
                                                 unsigned short* __restrict__ u) {
  const int wave = threadIdx.x >> 6, lane = threadIdx.x & 63;
  const int row = blockIdx.x * 4 + wave;
  const unsigned short* zr = abw + (size_t)row * 3072 + lane * 16;
  short8 z0 = *(const short8*)zr;
  short8 z1 = *(const short8*)(zr + 8);
  float x[16];
#pragma unroll
  for (int e = 0; e < 8; ++e) {
    x[e]     = b2f((unsigned short)z0[e]);
    x[8 + e] = b2f((unsigned short)z1[e]);
  }
  float s = 0.f, s2 = 0.f;
#pragma unroll
  for (int e = 0; e < 16; ++e) { s += x[e]; s2 += x[e] * x[e]; }
#pragma unroll
  for (int off = 32; off > 0; off >>= 1) {
    s += __shfl_xor(s, off, 64);
    s2 += __shfl_xor(s2, off, 64);
  }
  const float mu = s * (1.f / 1024.f);
  const float var = s2 * (1.f / 1024.f) - mu * mu;
  const float rs = rsqrtf(var + 1e-5f);
  const float* gp = gam + lane * 16;
  const float* bp = bet + lane * 16;
  short8 o0, o1;
#pragma unroll
  for (int e = 0; e < 8; ++e) {
    float v0 = x[e]     + (x[e]     - mu) * rs * gp[e]     + bp[e];
    float v1 = x[8 + e] + (x[8 + e] - mu) * rs * gp[8 + e] + bp[8 + e];
    o0[e] = (short)f2b(v0);
    o1[e] = (short)f2b(v1);
  }
  unsigned short* ur = u + (size_t)row * HID + lane * 16;
  *(short8*)ur = o0;
  *(short8*)(ur + 8) = o1;
}

// ---------------- launch ----------------
extern "C" void kernel_launch(void* const* d_in, const int* in_sizes, int n_in,
                              void* d_out, int out_size, void* d_ws, size_t ws_size,
                              hipStream_t stream) {
  if (ws_size < WS_NEEDED) return;

  const float* emb   = (const float*)d_in[0];
  const float* Wa_w  = (const float*)d_in[1];
  const float* Wa_b  = (const float*)d_in[2];
  const float* Wb_w  = (const float*)d_in[3];
  const float* Wb_b  = (const float*)d_in[4];
  const float* Wo_w  = (const float*)d_in[5];
  const float* Wo_b  = (const float*)d_in[6];
  const float* C_w   = (const float*)d_in[7];
  const float* C_b   = (const float*)d_in[8];
  const float* ln_g  = (const float*)d_in[9];
  const float* ln_b  = (const float*)d_in[10];
  const float* f1_w  = (const float*)d_in[11];
  const float* f1_b  = (const float*)d_in[12];
  const float* f2_w  = (const float*)d_in[13];
  const float* f2_b  = (const float*)d_in[14];
  const float* p_w   = (const float*)d_in[15];
  const float* p_b   = (const float*)d_in[16];
  const float* headw = (const float*)d_in[17];

  char* ws = (char*)d_ws;
  unsigned short* bfp  = (unsigned short*)ws;
  unsigned short* abwB = (unsigned short*)(ws + OFF_ABW);
  unsigned short* hB   = (unsigned short*)(ws + OFF_H);
  unsigned short* uB   = (unsigned short*)(ws + OFF_U);
  unsigned short* ffnB = abwB;                  // ffn [M][4096] spans abw+h
  float* agA = (float*)(ws + OFF_AGG);
  float* agB = agA + AG_ELEMS;
  float* pre = agB + AG_ELEMS;

  convert_all<<<2048, 256, 0, stream>>>(emb, Wa_w, Wb_w, Wo_w, C_w, f1_w, f2_w, p_w, bfp);

  // abw = [tanh(emb@Wa^T+ba) | emb@Wb^T+bb | emb@Wo^T+bo]
  gemm256<0><<<dim3(64, 12), 512, 0, stream>>>(
      bfp + ELN_EMB, bfp + ELN_WABO, 1024, 16, 3072, 0,
      Wa_b, Wb_b, Wo_b, nullptr, nullptr, nullptr, abwB);

  scan_p1<<<BB * NCH * 4, 256, 0, stream>>>(abwB, agA, agB);
  scan_p2<<<16, 256, 0, stream>>>(agA, agB, pre);
  scan_p3<<<BB * NCH * 4, 256, 0, stream>>>(abwB, pre, hB);

  // z = hw * (h@C^T + cb + w)
  gemm256<1><<<dim3(64, 4), 512, 0, stream>>>(
      hB, bfp + ELN_CW, 1024, 16, 3072, 3072,
      C_b, nullptr, nullptr, abwB + 2048, headw, nullptr, abwB);

  ln_kernel<<<4096, 256, 0, stream>>>(abwB, ln_g, ln_b, uB);

  // ffn = gelu(u@f1^T + b1)
  gemm256<2><<<dim3(64, 16), 512, 0, stream>>>(
      uB, bfp + ELN_F1, 1024, 16, 4096, 0,
      f1_b, nullptr, nullptr, nullptr, nullptr, nullptr, ffnB);

  // v = ffn@f2^T + b2 + u  (in-place over u)
  gemm256<3><<<dim3(64, 4), 512, 0, stream>>>(
      ffnB, bfp + ELN_F2, 4096, 64, 1024, 1024,
      f2_b, nullptr, nullptr, uB, nullptr, nullptr, uB);

  // out = v@p^T + pb  (f32)
  gemm256<4><<<dim3(64, 4), 512, 0, stream>>>(
      uB, bfp + ELN_PW, 1024, 16, 1024, 0,
      p_b, nullptr, nullptr, nullptr, nullptr, (float*)d_out, nullptr);
}